// Round 11
// baseline (69.814 us; speedup 1.0000x reference)
//
#include <hip/hip_runtime.h>
#include <math.h>

// E8S codebook quantization via 32x32x16 bf16 MFMA pairs, exact 3-way split.
//   scores[r][c] = 2*X[r]·G[c] - ||G[c]||^2 ; idx = first-argmax over c.
// Exactness: G coords multiples of 0.25 (exact bf16); 2*X = h+m+l exact
// 3-term bf16 split; gn multiple of 0.5 < 16 (exact bf16).
// Tile = 32 codewords x 32 rows. K=16 = 2 dim-groups of 8 (kg = lane>>5):
//   stage1: A=coords(both kg), B=(kg? m : h)        -> (h+m)·g
//   stage2: A=(kg? [gn,0..]:coords), B=(kg? [-1,0..]:l), C=stage1 -> +l·g - gn
// D layout (m74/m101): col=lane&31 (X row), cw_in_tile=(reg&3)+8*(reg>>2)+4*kg.
// R8: inline-asm MFMA keeps accumulators in arch VGPRs (no accvgpr churn).
// R11: per-MFMA serial max16 tree replaced by ELEMENT-WISE running max
// (16 independent fmax chains, no serial stall); tree collapse + (M, group)
// tracking amortized over 8-tile groups. MFMA issue floor = 891K x ~32
// SIMD-cyc = 11.7 us; VALU stream now < MFMA stream -> co-issue across 3
// waves/SIMD. Resolve rescans the winning group (<=8 tiles) bit-identically:
// smallest group among score-ties (atomic ~gid), ascending scan -> smallest
// index == np.argmax first-max. Partial groups at chunk splits are safe: the
// atomic merges partial group maxima; the winning group provably contains the
// global max and its first occurrence.

typedef short short8 __attribute__((ext_vector_type(8)));
typedef float f32x16 __attribute__((ext_vector_type(16)));

constexpr int NROWS  = 8192;
constexpr int NCW    = 55650;
constexpr int NT     = 1740;          // 32-codeword tiles
constexpr int NCWP   = NT * 32;       // 55680 (pads score ~ -3.4e38)
constexpr int NCHUNK = 24;            // tile chunks (grid.y)
constexpr int RBLK   = 32;            // row blocks of 256 rows (grid.x)

// workspace layout (bytes)
// Gb: [NCWP][16] ushort — 0..7 = bf16 coords, 8 = bf16 gn, 9..15 = 0
constexpr size_t OFF_GB = 0;
constexpr size_t OFF_XS = OFF_GB + (size_t)NCWP * 32;   // ushort Xs[NROWS*4*8]
constexpr size_t OFF_BK = OFF_XS + (size_t)NROWS * 64;  // u64 best[NROWS]

__device__ inline unsigned short bf16_rne(float f) {
  unsigned int u = __float_as_uint(f);
  unsigned int r = u + 0x7FFFu + ((u >> 16) & 1u);
  return (unsigned short)(r >> 16);
}
__device__ inline float bf16_f(unsigned short h) {
  return __uint_as_float(((unsigned int)h) << 16);
}
__device__ inline unsigned int enc_ord(float f) {  // monotonic float->uint
  unsigned int u = __float_as_uint(f);
  return (u & 0x80000000u) ? ~u : (u | 0x80000000u);
}
__device__ inline float dec_ord(unsigned int e) {
  unsigned int u = (e & 0x80000000u) ? (e & 0x7FFFFFFFu) : ~e;
  return __uint_as_float(u);
}
__device__ inline float max16(const f32x16& d) {   // max3-shaped tree
  float t1 = fmaxf(fmaxf(d[0], d[1]), d[2]);
  float t2 = fmaxf(fmaxf(d[3], d[4]), d[5]);
  float t3 = fmaxf(fmaxf(d[6], d[7]), d[8]);
  float t4 = fmaxf(fmaxf(d[9], d[10]), d[11]);
  float t5 = fmaxf(fmaxf(d[12], d[13]), d[14]);
  float u1 = fmaxf(fmaxf(t1, t2), t3);
  float u2 = fmaxf(fmaxf(t4, t5), d[15]);
  return fmaxf(u1, u2);
}

__global__ __launch_bounds__(256) void e8_prep(
    const float* __restrict__ X, const float* __restrict__ G,
    const float* __restrict__ GN, unsigned short* __restrict__ Gb,
    unsigned short* __restrict__ Xs, unsigned long long* __restrict__ best) {
  int i = blockIdx.x * 256 + threadIdx.x;
  if (i < NCWP) {
    unsigned short g16[16];
    if (i < NCW) {
      for (int j = 0; j < 8; ++j) g16[j] = bf16_rne(G[(size_t)i*8+j]);
      g16[8] = bf16_rne(GN[i]);         // exact: multiple of 0.5, < 16
      for (int j = 9; j < 16; ++j) g16[j] = 0;
    } else {
      for (int j = 0; j < 8; ++j) g16[j] = 0;
      g16[8] = 0x7F7F;                  // bf16 max finite -> score ~ -3.4e38
      for (int j = 9; j < 16; ++j) g16[j] = 0;
    }
    uint4* dst = reinterpret_cast<uint4*>(Gb + (size_t)i * 16);
    dst[0] = *reinterpret_cast<uint4*>(&g16[0]);
    dst[1] = *reinterpret_cast<uint4*>(&g16[8]);
  } else if (i < NCWP + NROWS) {
    int r = i - NCWP;
    unsigned short hh[8], mm[8], ll[8], qq[8];
    for (int j = 0; j < 8; ++j) {
      float s = 2.0f * X[(size_t)r*8+j];           // exact
      unsigned short h = bf16_rne(s);  float r1 = s  - bf16_f(h);  // exact
      unsigned short m = bf16_rne(r1); float r2 = r1 - bf16_f(m);  // exact
      unsigned short l = bf16_rne(r2);             // residual after 3 terms = 0
      hh[j] = h; mm[j] = m; ll[j] = l;
      qq[j] = (j == 0) ? (unsigned short)0xBF80 : 0;  // -1.0
    }
    uint4* dst = reinterpret_cast<uint4*>(Xs + (size_t)r * 32);
    dst[0] = *reinterpret_cast<uint4*>(hh);
    dst[1] = *reinterpret_cast<uint4*>(mm);
    dst[2] = *reinterpret_cast<uint4*>(ll);
    dst[3] = *reinterpret_cast<uint4*>(qq);
    best[r] = 0ull;   // below enc_ord of any real score
  }
}

// one tile step: prefetch next a-frags, 4 MFMAs (2 rows x 2 stages),
// element-wise running max into dm0/dm1 (FIRST=1 initializes the group).
#define E8_STEP(FIRST)                                                     \
  {                                                                        \
    p += 512;                                                              \
    short8 na1 = *reinterpret_cast<const short8*>(p);                      \
    short8 na2 = *reinterpret_cast<const short8*>(p + koff);               \
    f32x16 d0, d1;                                                         \
    asm volatile(                                                          \
        "v_mfma_f32_32x32x16_bf16 %0, %2, %4, %8\n\t"                      \
        "v_mfma_f32_32x32x16_bf16 %1, %2, %5, %8\n\t"                      \
        "v_mfma_f32_32x32x16_bf16 %0, %3, %6, %0\n\t"                      \
        "v_mfma_f32_32x32x16_bf16 %1, %3, %7, %1\n\t"                      \
        "s_nop 7\n\t"                                                      \
        "s_nop 7"                                                          \
        : "=&v"(d0), "=&v"(d1)                                             \
        : "v"(a1), "v"(a2), "v"(b10), "v"(b11), "v"(b20), "v"(b21),        \
          "v"(cz));                                                        \
    if (FIRST) {                                                           \
      dm0 = d0; dm1 = d1;                                                  \
    } else {                                                               \
      _Pragma("unroll")                                                    \
      for (int i = 0; i < 16; ++i) {                                       \
        dm0[i] = fmaxf(dm0[i], d0[i]);                                     \
        dm1[i] = fmaxf(dm1[i], d1[i]);                                     \
      }                                                                    \
    }                                                                      \
    a1 = na1; a2 = na2;                                                    \
  }

// Per block: 4 waves x 2 row-tiles = 64 rows/wave, chunk of ~72.5 cw-tiles.
// Grid 32x24 = 768 blocks = 3 blocks/CU = 3 waves/SIMD (VGPR cap 170).
__global__ __launch_bounds__(256, 3) void e8_main(
    const unsigned short* __restrict__ Gb,
    const unsigned short* __restrict__ Xs,
    unsigned long long* __restrict__ best) {
  const int lane = threadIdx.x & 63;
  const int wave = threadIdx.x >> 6;
  const int kg = lane >> 5, l31 = lane & 31;
  const int rowbase = blockIdx.x * 256 + wave * 64;

  short8 b10, b11, b20, b21;
  {
    const size_t row0 = (size_t)rowbase + l31;
    const size_t row1 = row0 + 32;
    b10 = *reinterpret_cast<const short8*>(Xs + (row0*4 + kg)*8);
    b20 = *reinterpret_cast<const short8*>(Xs + (row0*4 + 2 + kg)*8);
    b11 = *reinterpret_cast<const short8*>(Xs + (row1*4 + kg)*8);
    b21 = *reinterpret_cast<const short8*>(Xs + (row1*4 + 2 + kg)*8);
  }
  asm("" : "+v"(b10), "+v"(b11), "+v"(b20), "+v"(b21));  // keep resident

  const int ct0 = blockIdx.y * NT / NCHUNK;
  const int ct1 = (blockIdx.y + 1) * NT / NCHUNK;

  f32x16 cz;
#pragma unroll
  for (int i = 0; i < 16; ++i) cz[i] = 0.0f;

  float bs0 = -INFINITY, bs1 = -INFINITY;
  int   bi0 = 0,         bi1 = 0;

  const unsigned short* p = Gb + (size_t)ct0 * 512 + (size_t)l31 * 16 - 512;
  const int koff = kg << 3;   // a2 slice: coords (kg=0) or [gn,0..] (kg=1)

  short8 a1, a2;
  {  // prime the 1-deep pipeline with tile ct0
    p += 512;
    a1 = *reinterpret_cast<const short8*>(p);
    a2 = *reinterpret_cast<const short8*>(p + koff);
  }

  int ct = ct0;
  while (ct < ct1) {
    const int gend = ((ct | 7) + 1 < ct1) ? (ct | 7) + 1 : ct1;  // group end
    f32x16 dm0, dm1;
    E8_STEP(1)           // first tile of group initializes dm
    ++ct;
    for (; ct < gend; ++ct) E8_STEP(0)
    const int gid = (ct - 1) >> 3;      // global group id of this group
    const float m0 = max16(dm0);
    const float m1 = max16(dm1);
    bi0 = (m0 > bs0) ? gid : bi0;       // strict > -> earliest group wins
    bs0 = fmaxf(bs0, m0);
    bi1 = (m1 > bs1) ? gid : bi1;
    bs1 = fmaxf(bs1, m1);
  }

  {
    unsigned long long key =
        ((unsigned long long)enc_ord(bs0) << 32) | (unsigned int)(~bi0);
    unsigned long long o = __shfl_xor(key, 32, 64);
    key = (o > key) ? o : key;          // merge the two kg half-sets of a row
    if (lane < 32) atomicMax(&best[(size_t)rowbase + l31], key);
  }
  {
    unsigned long long key =
        ((unsigned long long)enc_ord(bs1) << 32) | (unsigned int)(~bi1);
    unsigned long long o = __shfl_xor(key, 32, 64);
    key = (o > key) ? o : key;
    if (lane < 32) atomicMax(&best[(size_t)rowbase + 32 + l31], key);
  }
}

// 512 blocks x 4 waves; wave handles 4 rows of its 32-row tile: re-run the
// bit-identical MFMA chain over the winning GROUP's <=8 tiles, take the
// smallest matching global index, write the output row (vals + idx).
__global__ __launch_bounds__(256) void e8_resolve(
    const unsigned short* __restrict__ Gb,
    const unsigned short* __restrict__ Xs, const float* __restrict__ G,
    const unsigned long long* __restrict__ best, float* __restrict__ out) {
  const int lane = threadIdx.x & 63;
  const int wave = threadIdx.x >> 6;
  const int kg = lane >> 5, l31 = lane & 31;
  const int rt   = blockIdx.x >> 1;       // 0..255 (32-row tile)
  const int half = blockIdx.x & 1;        // rows 0-15 / 16-31 of the tile

  short8 b1, b2;
  {
    const size_t row = (size_t)rt * 32 + l31;
    b1 = *reinterpret_cast<const short8*>(Xs + (row*4 + kg)*8);
    b2 = *reinterpret_cast<const short8*>(Xs + (row*4 + 2 + kg)*8);
  }
  f32x16 cz;
#pragma unroll
  for (int i = 0; i < 16; ++i) cz[i] = 0.0f;

  const int jbeg = half * 16 + wave * 4;
  for (int j = jbeg; j < jbeg + 4; ++j) {
    const int srow = rt * 32 + j;
    const unsigned long long k = best[srow];
    const float sstar = dec_ord((unsigned int)(k >> 32));
    const int gwin = (int)(~(unsigned int)(k & 0xFFFFFFFFull));

    const int t0 = gwin * 8;
    const int t1 = (t0 + 8 < NT) ? t0 + 8 : NT;
    int cand = 0x7FFFFFFF;
    for (int tt = t0; tt < t1; ++tt) {
      const unsigned short* ga = Gb + (size_t)tt * 512 + (size_t)l31 * 16;
      short8 a1 = *reinterpret_cast<const short8*>(ga);
      short8 a2 = *reinterpret_cast<const short8*>(ga + (kg << 3));
      f32x16 d = __builtin_amdgcn_mfma_f32_32x32x16_bf16(a1, b1, cz, 0, 0, 0);
      d = __builtin_amdgcn_mfma_f32_32x32x16_bf16(a2, b2, d, 0, 0, 0);

      int tc = 0x0FFFFFFF;
#pragma unroll
      for (int r = 15; r >= 0; --r)     // descending -> smallest slot wins
        tc = (d[r] == sstar) ? ((r & 3) + 8 * (r >> 2)) : tc;
      const int gidx = tt * 32 + 4 * kg + tc;   // huge if no match
      cand = (gidx < cand) ? gidx : cand;       // tiles ascend -> first match
    }
    if (l31 != j) cand = 0x7FFFFFFF;    // only this row's two lanes count
    const int o = __shfl_xor(cand, 32, 64);
    cand = min(cand, o);
    if (lane == j) {
      const float4* g = reinterpret_cast<const float4*>(G + (size_t)cand * 8);
      float4 v0 = g[0], v1 = g[1];
      float4* od = reinterpret_cast<float4*>(out + (size_t)srow * 8);
      od[0] = v0; od[1] = v1;
      out[(size_t)NROWS * 8 + srow] = (float)(cand - 32768);
    }
  }
}

extern "C" void kernel_launch(void* const* d_in, const int* in_sizes, int n_in,
                              void* d_out, int out_size, void* d_ws, size_t ws_size,
                              hipStream_t stream) {
  const float* X  = (const float*)d_in[0];
  const float* G  = (const float*)d_in[1];
  const float* GN = (const float*)d_in[2];
  float* out = (float*)d_out;

  char* ws = (char*)d_ws;
  unsigned short*     Gb   = (unsigned short*)(ws + OFF_GB);
  unsigned short*     Xs   = (unsigned short*)(ws + OFF_XS);
  unsigned long long* best = (unsigned long long*)(ws + OFF_BK);

  e8_prep<<<(NCWP + NROWS + 255) / 256, 256, 0, stream>>>(X, G, GN, Gb, Xs, best);
  e8_main<<<dim3(RBLK, NCHUNK), 256, 0, stream>>>(Gb, Xs, best);
  e8_resolve<<<512, 256, 0, stream>>>(Gb, Xs, G, best, out);
}

// Round 12
// 43.579 us; speedup vs baseline: 1.6020x; 1.6020x over previous
//
#include <hip/hip_runtime.h>
#include <math.h>

// E8S codebook quantization via 32x32x16 bf16 MFMA pairs, exact 3-way split.
//   scores[r][c] = 2*X[r]·G[c] - ||G[c]||^2 ; idx = first-argmax over c.
// Exactness: G coords multiples of 0.25 (exact bf16); 2*X = h+m+l exact
// 3-term bf16 split; gn multiple of 0.5 < 16 (exact bf16).
// Tile = 32 codewords x 32 rows. K=16 = 2 dim-groups of 8 (kg = lane>>5):
//   stage1: A=coords(both kg), B=(kg? m : h)        -> (h+m)·g
//   stage2: A=(kg? [gn,0..]:coords), B=(kg? [-1,0..]:l), C=stage1 -> +l·g - gn
// D layout (m74/m101): col=lane&31 (X row), cw_in_tile=(reg&3)+8*(reg>>2)+4*kg.
// R8: inline-asm MFMA keeps accumulators in arch VGPRs.
// R12: DOUBLE-BUFFERED d accumulators (dE/dO) kill the per-iteration WAR
// hazard (R8-R11: same "=&v" regs each iter => next MFMA waited on the max
// tree). Tree for tile t now runs after the asm for tile t+1 (empty-asm pin
// "+v"(dE):"v"(dO) enforces order) => MFMA issue overlaps tree+latency; with
// 3 waves/SIMD the matrix pipe approaches the 11.7us floor. Per-tile (val,
// ~tile) tracking; resolve re-runs the winning tile bit-identically.

typedef short short8 __attribute__((ext_vector_type(8)));
typedef float f32x16 __attribute__((ext_vector_type(16)));

constexpr int NROWS  = 8192;
constexpr int NCW    = 55650;
constexpr int NT     = 1740;          // 32-codeword tiles
constexpr int NCWP   = NT * 32;       // 55680 (pads score ~ -3.4e38)
constexpr int NCHUNK = 24;            // tile chunks (grid.y)
constexpr int RBLK   = 32;            // row blocks of 256 rows (grid.x)

// workspace layout (bytes)
// Gb: [NCWP][16] ushort — 0..7 = bf16 coords, 8 = bf16 gn, 9..15 = 0
constexpr size_t OFF_GB = 0;
constexpr size_t OFF_XS = OFF_GB + (size_t)NCWP * 32;   // ushort Xs[NROWS*4*8]
constexpr size_t OFF_BK = OFF_XS + (size_t)NROWS * 64;  // u64 best[NROWS]

__device__ inline unsigned short bf16_rne(float f) {
  unsigned int u = __float_as_uint(f);
  unsigned int r = u + 0x7FFFu + ((u >> 16) & 1u);
  return (unsigned short)(r >> 16);
}
__device__ inline float bf16_f(unsigned short h) {
  return __uint_as_float(((unsigned int)h) << 16);
}
__device__ inline unsigned int enc_ord(float f) {  // monotonic float->uint
  unsigned int u = __float_as_uint(f);
  return (u & 0x80000000u) ? ~u : (u | 0x80000000u);
}
__device__ inline float dec_ord(unsigned int e) {
  unsigned int u = (e & 0x80000000u) ? (e & 0x7FFFFFFFu) : ~e;
  return __uint_as_float(u);
}
__device__ inline float max16(const f32x16& d) {
  float t1 = fmaxf(fmaxf(d[0], d[1]), d[2]);
  float t2 = fmaxf(fmaxf(d[3], d[4]), d[5]);
  float t3 = fmaxf(fmaxf(d[6], d[7]), d[8]);
  float t4 = fmaxf(fmaxf(d[9], d[10]), d[11]);
  float t5 = fmaxf(fmaxf(d[12], d[13]), d[14]);
  float u1 = fmaxf(fmaxf(t1, t2), t3);
  float u2 = fmaxf(fmaxf(t4, t5), d[15]);
  return fmaxf(u1, u2);
}

__global__ __launch_bounds__(256) void e8_prep(
    const float* __restrict__ X, const float* __restrict__ G,
    const float* __restrict__ GN, unsigned short* __restrict__ Gb,
    unsigned short* __restrict__ Xs, unsigned long long* __restrict__ best) {
  int i = blockIdx.x * 256 + threadIdx.x;
  if (i < NCWP) {
    unsigned short g16[16];
    if (i < NCW) {
      for (int j = 0; j < 8; ++j) g16[j] = bf16_rne(G[(size_t)i*8+j]);
      g16[8] = bf16_rne(GN[i]);         // exact: multiple of 0.5, < 16
      for (int j = 9; j < 16; ++j) g16[j] = 0;
    } else {
      for (int j = 0; j < 8; ++j) g16[j] = 0;
      g16[8] = 0x7F7F;                  // bf16 max finite -> score ~ -3.4e38
      for (int j = 9; j < 16; ++j) g16[j] = 0;
    }
    uint4* dst = reinterpret_cast<uint4*>(Gb + (size_t)i * 16);
    dst[0] = *reinterpret_cast<uint4*>(&g16[0]);
    dst[1] = *reinterpret_cast<uint4*>(&g16[8]);
  } else if (i < NCWP + NROWS) {
    int r = i - NCWP;
    unsigned short hh[8], mm[8], ll[8], qq[8];
    for (int j = 0; j < 8; ++j) {
      float s = 2.0f * X[(size_t)r*8+j];           // exact
      unsigned short h = bf16_rne(s);  float r1 = s  - bf16_f(h);  // exact
      unsigned short m = bf16_rne(r1); float r2 = r1 - bf16_f(m);  // exact
      unsigned short l = bf16_rne(r2);             // residual after 3 terms = 0
      hh[j] = h; mm[j] = m; ll[j] = l;
      qq[j] = (j == 0) ? (unsigned short)0xBF80 : 0;  // -1.0
    }
    uint4* dst = reinterpret_cast<uint4*>(Xs + (size_t)r * 32);
    dst[0] = *reinterpret_cast<uint4*>(hh);
    dst[1] = *reinterpret_cast<uint4*>(mm);
    dst[2] = *reinterpret_cast<uint4*>(ll);
    dst[3] = *reinterpret_cast<uint4*>(qq);
    best[r] = 0ull;   // below enc_ord of any real score
  }
}

// 4 MFMAs for one 32cw x 64row tile-step into (D0,D1); a-frags A1/A2.
#define E8_ASM(D0, D1, A1, A2)                                             \
  asm volatile(                                                            \
      "v_mfma_f32_32x32x16_bf16 %0, %2, %4, %8\n\t"                        \
      "v_mfma_f32_32x32x16_bf16 %1, %2, %5, %8\n\t"                        \
      "v_mfma_f32_32x32x16_bf16 %0, %3, %6, %0\n\t"                        \
      "v_mfma_f32_32x32x16_bf16 %1, %3, %7, %1\n\t"                        \
      "s_nop 7\n\t"                                                        \
      "s_nop 7"                                                            \
      : "=&v"(D0), "=&v"(D1)                                               \
      : "v"(A1), "v"(A2), "v"(b10), "v"(b11), "v"(b20), "v"(b21), "v"(cz))

// order pin: (P0,P1) may only be reduced after the asm that wrote T0.
#define E8_PIN(P0, P1, T0) asm("" : "+v"(P0), "+v"(P1) : "v"(T0))

#define E8_LOAD(A1, A2)                                                    \
  A1 = *reinterpret_cast<const short8*>(p);                                \
  A2 = *reinterpret_cast<const short8*>(p + koff);                         \
  p += 512;

#define E8_TRACK(D0, D1, TILE)                                             \
  {                                                                        \
    const float m0 = max16(D0);                                            \
    const float m1 = max16(D1);                                            \
    bi0 = (m0 > bs0) ? (TILE) : bi0;  bs0 = fmaxf(bs0, m0);                \
    bi1 = (m1 > bs1) ? (TILE) : bi1;  bs1 = fmaxf(bs1, m1);                \
  }

// Per block: 4 waves x 2 row-tiles = 256 rows, chunk of ~72.5 cw-tiles.
// Grid 32x24 = 768 blocks = 3 blocks/CU = 3 waves/SIMD.
__global__ __launch_bounds__(256, 3) void e8_main(
    const unsigned short* __restrict__ Gb,
    const unsigned short* __restrict__ Xs,
    unsigned long long* __restrict__ best) {
  const int lane = threadIdx.x & 63;
  const int wave = threadIdx.x >> 6;
  const int kg = lane >> 5, l31 = lane & 31;
  const int rowbase = blockIdx.x * 256 + wave * 64;

  short8 b10, b11, b20, b21;
  {
    const size_t row0 = (size_t)rowbase + l31;
    const size_t row1 = row0 + 32;
    b10 = *reinterpret_cast<const short8*>(Xs + (row0*4 + kg)*8);
    b20 = *reinterpret_cast<const short8*>(Xs + (row0*4 + 2 + kg)*8);
    b11 = *reinterpret_cast<const short8*>(Xs + (row1*4 + kg)*8);
    b21 = *reinterpret_cast<const short8*>(Xs + (row1*4 + 2 + kg)*8);
  }
  asm("" : "+v"(b10), "+v"(b11), "+v"(b20), "+v"(b21));

  const int ct0 = blockIdx.y * NT / NCHUNK;
  const int ct1 = (blockIdx.y + 1) * NT / NCHUNK;

  f32x16 cz;
#pragma unroll
  for (int i = 0; i < 16; ++i) cz[i] = 0.0f;

  float bs0 = -INFINITY, bs1 = -INFINITY;
  int   bi0 = 0,         bi1 = 0;

  const unsigned short* p = Gb + (size_t)ct0 * 512 + (size_t)l31 * 16;
  const int koff = kg << 3;   // a2 slice: coords (kg=0) or [gn,0..] (kg=1)

  short8 aE1, aE2, aO1, aO2;
  f32x16 dE0, dE1, dO0, dO1;

  // prologue: tile ct0 into dE; prefetch ct0+1 into aO
  E8_LOAD(aE1, aE2)
  E8_LOAD(aO1, aO2)
  E8_ASM(dE0, dE1, aE1, aE2);

  int k = ct0 + 1;
  for (; k + 1 < ct1; k += 2) {
    // tile k into dO (uses aO), prefetch k+1 into aE
    E8_LOAD(aE1, aE2)
    E8_ASM(dO0, dO1, aO1, aO2);
    E8_PIN(dE0, dE1, dO0);
    E8_TRACK(dE0, dE1, k - 1)          // tile k-1 (even buffer)
    // tile k+1 into dE (uses aE), prefetch k+2 into aO
    E8_LOAD(aO1, aO2)
    E8_ASM(dE0, dE1, aE1, aE2);
    E8_PIN(dO0, dO1, dE0);
    E8_TRACK(dO0, dO1, k)              // tile k (odd buffer)
  }

  if ((ct1 - ct0 - 1) & 1) {
    // one tile left: ct1-1 (a-frags already in aO)
    E8_ASM(dO0, dO1, aO1, aO2);
    E8_PIN(dE0, dE1, dO0);
    E8_TRACK(dE0, dE1, ct1 - 2)
    E8_TRACK(dO0, dO1, ct1 - 1)
  } else {
    E8_TRACK(dE0, dE1, ct1 - 1)
  }

  {
    unsigned long long key =
        ((unsigned long long)enc_ord(bs0) << 32) | (unsigned int)(~bi0);
    unsigned long long o = __shfl_xor(key, 32, 64);
    key = (o > key) ? o : key;          // merge the two kg half-sets of a row
    if (lane < 32) atomicMax(&best[(size_t)rowbase + l31], key);
  }
  {
    unsigned long long key =
        ((unsigned long long)enc_ord(bs1) << 32) | (unsigned int)(~bi1);
    unsigned long long o = __shfl_xor(key, 32, 64);
    key = (o > key) ? o : key;
    if (lane < 32) atomicMax(&best[(size_t)rowbase + 32 + l31], key);
  }
}

// 256 blocks x 4 waves; wave handles 8 rows of its 32-row tile: re-run the
// bit-identical MFMA chain on each row's winning tile, find smallest matching
// index, and write the output row (vals + idx) directly.
__global__ __launch_bounds__(256) void e8_resolve(
    const unsigned short* __restrict__ Gb,
    const unsigned short* __restrict__ Xs, const float* __restrict__ G,
    const unsigned long long* __restrict__ best, float* __restrict__ out) {
  const int lane = threadIdx.x & 63;
  const int wave = threadIdx.x >> 6;
  const int kg = lane >> 5, l31 = lane & 31;
  const int rt = blockIdx.x;              // 0..255

  short8 b1, b2;
  {
    const size_t row = (size_t)rt * 32 + l31;
    b1 = *reinterpret_cast<const short8*>(Xs + (row*4 + kg)*8);
    b2 = *reinterpret_cast<const short8*>(Xs + (row*4 + 2 + kg)*8);
  }
  f32x16 cz;
#pragma unroll
  for (int i = 0; i < 16; ++i) cz[i] = 0.0f;

  for (int j = wave * 8; j < wave * 8 + 8; ++j) {
    const int srow = rt * 32 + j;
    const unsigned long long k = best[srow];
    const float sstar = dec_ord((unsigned int)(k >> 32));
    const int twin = (int)(~(unsigned int)(k & 0xFFFFFFFFull));

    const unsigned short* ga = Gb + (size_t)twin * 512 + (size_t)l31 * 16;
    short8 a1 = *reinterpret_cast<const short8*>(ga);
    short8 a2 = *reinterpret_cast<const short8*>(ga + (kg << 3));
    f32x16 d = __builtin_amdgcn_mfma_f32_32x32x16_bf16(a1, b1, cz, 0, 0, 0);
    d = __builtin_amdgcn_mfma_f32_32x32x16_bf16(a2, b2, d, 0, 0, 0);

    const int base = twin * 32 + 4 * kg;
    int cand = 0x7FFFFFFF;
#pragma unroll
    for (int r = 15; r >= 0; --r)       // descending -> smallest slot wins
      cand = (d[r] == sstar) ? (base + ((r & 3) + 8 * (r >> 2))) : cand;
    if (l31 != j) cand = 0x7FFFFFFF;    // only this row's two lanes count
    const int o = __shfl_xor(cand, 32, 64);
    cand = min(cand, o);
    if (lane == j) {
      const float4* g = reinterpret_cast<const float4*>(G + (size_t)cand * 8);
      float4 v0 = g[0], v1 = g[1];
      float4* od = reinterpret_cast<float4*>(out + (size_t)srow * 8);
      od[0] = v0; od[1] = v1;
      out[(size_t)NROWS * 8 + srow] = (float)(cand - 32768);
    }
  }
}

extern "C" void kernel_launch(void* const* d_in, const int* in_sizes, int n_in,
                              void* d_out, int out_size, void* d_ws, size_t ws_size,
                              hipStream_t stream) {
  const float* X  = (const float*)d_in[0];
  const float* G  = (const float*)d_in[1];
  const float* GN = (const float*)d_in[2];
  float* out = (float*)d_out;

  char* ws = (char*)d_ws;
  unsigned short*     Gb   = (unsigned short*)(ws + OFF_GB);
  unsigned short*     Xs   = (unsigned short*)(ws + OFF_XS);
  unsigned long long* best = (unsigned long long*)(ws + OFF_BK);

  e8_prep<<<(NCWP + NROWS + 255) / 256, 256, 0, stream>>>(X, G, GN, Gb, Xs, best);
  e8_main<<<dim3(RBLK, NCHUNK), 256, 0, stream>>>(Gb, Xs, best);
  e8_resolve<<<256, 256, 0, stream>>>(Gb, Xs, G, best, out);
}